// Round 3
// baseline (828.459 us; speedup 1.0000x reference)
//
#include <hip/hip_runtime.h>
#include <cstdint>
#include <cstddef>

// ---------------------------------------------------------------------------
// SSTAFormer round 3: LDS-arena shrink (6 wg/CU), register-hoisted fragments,
// LDS-staged k_heads.  1 wave = 1 graph; no __syncthreads in k_fused.
// ---------------------------------------------------------------------------

typedef __attribute__((ext_vector_type(8))) __bf16 bf16x8;
typedef __attribute__((ext_vector_type(4))) float  f32x4;

#define MFMA16(a,b,c) __builtin_amdgcn_mfma_f32_16x16x32_bf16((a),(b),(c),0,0,0)
#define FENCE() __threadfence_block()

#define NGR    16384
#define EDGES  1048576
#define PRED_ELEMS (16*16384*24)

// workspace layout in ushort units
#define O_W1L 0               // [128][192]
#define O_W1R 24576
#define O_W2L 49152           // [128][128]
#define O_W2R 65536
#define O_W3L 81920           // [64][128]
#define O_W3R 90112
#define O_T0  98304           // [64 co][64 ci]
#define O_T1  102400
#define O_WQ  106496          // [64][64]
#define O_WK  110592
#define O_WV  114688
#define O_WO  118784
#define O_FC1 122880          // 16 x [64][128]
#define O_FC2 253952          // 16 x [32][64]
#define O_FEAT 286720         // [16384][128] bf16
#define PREP_TOT 286720

// k_fused per-wave LDS arena (ushort offsets)
#define ARENA  3392
#define A_HB   0      // [16][136] phase A h buffer
#define A_UT   2176   // [16][24]+32 u^T block stage
#define A_X    0      // [16][72]
#define A_T    1152   // [16][72]
#define A_Q    0      // [16][72] over X
#define A_KR   1152   // [16][72] over T
#define A_VT   2304   // [64][16]+32 over UT tail
#define A_PB   0      // [64][16]+32 over Q
#define A_OST  1152   // [16][72] over Kr
#define A_PART 2304   // floats, over VT

static __device__ __forceinline__ unsigned short f2bf(float f){
  unsigned int u = __builtin_bit_cast(unsigned int, f);
  u += 0x7FFFu + ((u >> 16) & 1u);            // RNE
  return (unsigned short)(u >> 16);
}
static __device__ __forceinline__ float bf2f(unsigned short h){
  return __builtin_bit_cast(float, (unsigned int)h << 16);
}
static __device__ __forceinline__ bf16x8 ld8(const unsigned short* p){
  return __builtin_bit_cast(bf16x8, *(const uint4*)p);   // 16B-aligned by layout
}
static __device__ __forceinline__ bf16x8 zero8(){
  uint4 u = make_uint4(0u,0u,0u,0u);
  return __builtin_bit_cast(bf16x8, u);
}
static __device__ __forceinline__ ushort4 pack4(f32x4 v){
  ushort4 p; p.x=f2bf(v[0]); p.y=f2bf(v[1]); p.z=f2bf(v[2]); p.w=f2bf(v[3]); return p;
}
static __device__ __forceinline__ unsigned int pack2(float a, float b){
  return (unsigned int)f2bf(a) | ((unsigned int)f2bf(b) << 16);
}
static __device__ __forceinline__ bf16x8 xfrag(const float* __restrict__ xrow, int k0){
  int ks = (k0 < 168) ? k0 : 0;          // clamped lanes hit zero W rows
  float4 f0 = *(const float4*)(xrow + ks);
  float4 f1 = *(const float4*)(xrow + ks + 4);
  union { unsigned short s[8]; bf16x8 v; } u;
  u.s[0]=f2bf(f0.x); u.s[1]=f2bf(f0.y); u.s[2]=f2bf(f0.z); u.s[3]=f2bf(f0.w);
  u.s[4]=f2bf(f1.x); u.s[5]=f2bf(f1.y); u.s[6]=f2bf(f1.z); u.s[7]=f2bf(f1.w);
  return u.v;
}

// ---------------------------------------------------------------------------
// weight prep (unchanged, verified)
// ---------------------------------------------------------------------------
__global__ __launch_bounds__(256) void k_prep(
  const float* __restrict__ w1l, const float* __restrict__ w1r,
  const float* __restrict__ w2l, const float* __restrict__ w2r,
  const float* __restrict__ w3l, const float* __restrict__ w3r,
  const float* __restrict__ tcnw,
  const float* __restrict__ wq, const float* __restrict__ wk,
  const float* __restrict__ wv, const float* __restrict__ wo,
  const float* __restrict__ fc1w, const float* __restrict__ fc2w,
  unsigned short* __restrict__ W)
{
  int idx = blockIdx.x*256 + threadIdx.x;
  if (idx >= PREP_TOT) return;
  float v;
  if      (idx <  24576){ int t=idx;        int n=t/192,k=t%192; v=(k<168)? w1l[k*128+n]:0.f; }
  else if (idx <  49152){ int t=idx- 24576; int n=t/192,k=t%192; v=(k<168)? w1r[k*128+n]:0.f; }
  else if (idx <  65536){ int t=idx- 49152; int n=t/128,k=t%128; v=w2l[k*128+n]; }
  else if (idx <  81920){ int t=idx- 65536; int n=t/128,k=t%128; v=w2r[k*128+n]; }
  else if (idx <  90112){ int t=idx- 81920; int n=t/128,k=t%128; v=w3l[k*64+n]; }
  else if (idx <  98304){ int t=idx- 90112; int n=t/128,k=t%128; v=w3r[k*64+n]; }
  else if (idx < 102400){ int t=idx- 98304; int n=t/64, k=t%64;  v=tcnw[(n*64+k)*2+0]; }
  else if (idx < 106496){ int t=idx-102400; int n=t/64, k=t%64;  v=tcnw[(n*64+k)*2+1]; }
  else if (idx < 110592){ int t=idx-106496; int n=t/64, k=t%64;  v=wq[k*64+n]; }
  else if (idx < 114688){ int t=idx-110592; int n=t/64, k=t%64;  v=wk[k*64+n]; }
  else if (idx < 118784){ int t=idx-114688; int n=t/64, k=t%64;  v=wv[k*64+n]; }
  else if (idx < 122880){ int t=idx-118784; int n=t/64, k=t%64;  v=wo[k*64+n]; }
  else if (idx < 253952){ int t=idx-122880; int kh=t/8192, r=t%8192, n=r/128, k=r%128;
                          v=fc1w[kh*8192 + k*64 + n]; }
  else                  { int t=idx-253952; int kh=t/2048, r=t%2048, n=r/64,  k=r%64;
                          v=(n<24)? fc2w[kh*1536 + k*24 + n] : 0.f; }
  W[idx] = f2bf(v);
}

// ---------------------------------------------------------------------------
// fused GNN + TCN + attention + proj
// ---------------------------------------------------------------------------
__global__ __launch_bounds__(256,8) void k_fused(
  const float* __restrict__ x, const int* __restrict__ edst,
  const float* __restrict__ b1, const float* __restrict__ b2,
  const float* __restrict__ b3, const float* __restrict__ tcnb,
  const float* __restrict__ wproj, const float* __restrict__ bproj,
  const unsigned short* __restrict__ ws0, unsigned short* __restrict__ feat)
{
  __shared__ alignas(16) unsigned short pool[4*ARENA];
  const int tid=threadIdx.x, w=tid>>6, lane=tid&63, quad=lane>>4, l15=lane&15;
  unsigned short* AR = pool + w*ARENA;
  const int gb = blockIdx.x*4 + w, nb = gb*16;

  unsigned short* Hb = AR + A_HB;
  unsigned short* UT = AR + A_UT;

  const bf16x8 Z = zero8();
  const f32x4  z = {0.f,0.f,0.f,0.f};
  const bool hv = (quad < 2);

  // ---- adjacency A-fragment built fully in registers (4+2+4 shfls) ----
  bf16x8 aA;
  {
    int dloc = edst[gb*64 + lane] & 15;
    float c4[4]; float csum = 0.f;
    #pragma unroll
    for (int ss=0; ss<4; ++ss){
      int s = quad*4 + ss; int cc = 0;
      #pragma unroll
      for (int k=0;k<4;++k) cc += (__shfl(dloc, s*4+k, 64) == l15) ? 1 : 0;
      c4[ss] = (float)cc; csum += (float)cc;
    }
    csum += __shfl_xor(csum, 16, 64);
    csum += __shfl_xor(csum, 32, 64);
    float ainv = 1.f / fmaxf(csum, 1.f);
    unsigned int p0 = pack2(c4[0]*ainv, c4[1]*ainv);   // cols quad*4+0,+1 of row l15
    unsigned int p1 = pack2(c4[2]*ainv, c4[3]*ainv);   // cols quad*4+2,+3
    int q0 = hv ? 2*quad : 0;
    unsigned int a0 = __shfl((int)p0, q0*16+l15, 64);
    unsigned int a1 = __shfl((int)p1, q0*16+l15, 64);
    unsigned int a2 = __shfl((int)p0, (q0+1)*16+l15, 64);
    unsigned int a3 = __shfl((int)p1, (q0+1)*16+l15, 64);
    uint4 av = hv ? make_uint4(a0,a1,a2,a3) : make_uint4(0u,0u,0u,0u);
    aA = __builtin_bit_cast(bf16x8, av);               // A[m=l15][k=quad*8+j], 0 for k>=16
  }

  // ---- SAGE layer 1: K=168 (pad 192), x-frags held in regs ----
  {
    const float* xrow = x + (size_t)(nb + l15) * 168;
    bf16x8 xf[6];
    #pragma unroll
    for (int kc=0;kc<6;++kc) xf[kc] = xfrag(xrow, kc*32 + quad*8);
    const unsigned short* Wl = ws0 + O_W1L;
    const unsigned short* Wr = ws0 + O_W1R;
    #pragma unroll
    for (int c=0;c<8;++c){
      f32x4 accu = z;
      #pragma unroll
      for (int kc=0;kc<6;++kc)
        accu = MFMA16(xf[kc], ld8(Wl + (c*16+l15)*192 + kc*32+quad*8), accu);
      *(ushort4*)(UT + l15*24 + quad*4) = pack4(accu);     // u^T block: [col l15][node]
      f32x4 accv = z;
      #pragma unroll
      for (int kc=0;kc<6;++kc)
        accv = MFMA16(xf[kc], ld8(Wr + (c*16+l15)*192 + kc*32+quad*8), accv);
      accv = MFMA16(aA, ld8(UT + l15*24 + quad*8), accv);  // + A @ u
      float bb = b1[c*16+l15];
      #pragma unroll
      for (int r=0;r<4;++r)
        Hb[(quad*4+r)*136 + c*16+l15] = f2bf(fmaxf(accv[r]+bb, 0.f));
    }
  }
  FENCE();

  // ---- SAGE layers 2,3: input frags hoisted -> in-place Hb update ----
  #pragma unroll 1
  for (int layer=0; layer<2; ++layer){
    const unsigned short* Wl = ws0 + (layer==0 ? O_W2L : O_W3L);
    const unsigned short* Wr = ws0 + (layer==0 ? O_W2R : O_W3R);
    const float* bb_g        = (layer==0 ? b2 : b3);
    const int NC             = (layer==0 ? 8 : 4);
    bf16x8 hf[4];
    #pragma unroll
    for (int kc=0;kc<4;++kc) hf[kc] = ld8(Hb + l15*136 + kc*32+quad*8);
    FENCE();                                   // frags in regs; Hb now writable
    for (int c=0;c<NC;++c){
      f32x4 accu = z;
      #pragma unroll
      for (int kc=0;kc<4;++kc)
        accu = MFMA16(hf[kc], ld8(Wl + (c*16+l15)*128 + kc*32+quad*8), accu);
      *(ushort4*)(UT + l15*24 + quad*4) = pack4(accu);
      f32x4 accv = z;
      #pragma unroll
      for (int kc=0;kc<4;++kc)
        accv = MFMA16(hf[kc], ld8(Wr + (c*16+l15)*128 + kc*32+quad*8), accv);
      accv = MFMA16(aA, ld8(UT + l15*24 + quad*8), accv);
      float bb = bb_g[c*16+l15];
      if (layer==0){
        #pragma unroll
        for (int r=0;r<4;++r)
          Hb[(quad*4+r)*136 + c*16+l15] = f2bf(fmaxf(accv[r]+bb, 0.f));
      } else {
        // layer 3: no relu; write X[16][72]
        #pragma unroll
        for (int r=0;r<4;++r)
          AR[A_X + (quad*4+r)*72 + c*16+l15] = f2bf(accv[r]+bb);
      }
    }
    FENCE();
  }

  // residual values (exact bf16-rounded X) re-read per lane's C-layout cells
  unsigned short* X = AR + A_X;
  float xres[4][4];
  #pragma unroll
  for (int c=0;c<4;++c)
    #pragma unroll
    for (int r=0;r<4;++r)
      xres[c][r] = bf2f(X[(quad*4+r)*72 + c*16+l15]);

  // ---- TCN: t = relu(Xshift@W0 + X@W1 + tcn_b) + X ----
  unsigned short* T = AR + A_T;
  {
    f32x4 acct[4] = {z,z,z,z};
    #pragma unroll
    for (int kc=0;kc<2;++kc){
      bf16x8 ax  = ld8(X + l15*72 + kc*32+quad*8);
      bf16x8 as_ = (l15>0) ? ld8(X + (l15-1)*72 + kc*32+quad*8) : Z;
      #pragma unroll
      for (int c=0;c<4;++c){
        acct[c] = MFMA16(as_, ld8(ws0+O_T0 + (c*16+l15)*64 + kc*32+quad*8), acct[c]);
        acct[c] = MFMA16(ax,  ld8(ws0+O_T1 + (c*16+l15)*64 + kc*32+quad*8), acct[c]);
      }
    }
    #pragma unroll
    for (int c=0;c<4;++c){
      float tb = tcnb[c*16+l15];
      #pragma unroll
      for (int r=0;r<4;++r)
        T[(quad*4+r)*72 + c*16+l15] = f2bf(fmaxf(acct[c][r]+tb, 0.f) + xres[c][r]);
    }
  }
  FENCE();

  // ---- QKV: Q,K row-major [16][72]; V transposed [64][16] ----
  unsigned short* Q  = AR + A_Q;
  unsigned short* Kr = AR + A_KR;
  unsigned short* VT = AR + A_VT;
  {
    bf16x8 tf[2];
    tf[0] = ld8(T + l15*72 + quad*8);
    tf[1] = ld8(T + l15*72 + 32 + quad*8);
    f32x4 aq[4]={z,z,z,z}, ak[4]={z,z,z,z}, av[4]={z,z,z,z};
    #pragma unroll
    for (int kc=0;kc<2;++kc){
      #pragma unroll
      for (int c=0;c<4;++c){
        aq[c] = MFMA16(tf[kc], ld8(ws0+O_WQ + (c*16+l15)*64 + kc*32+quad*8), aq[c]);
        ak[c] = MFMA16(tf[kc], ld8(ws0+O_WK + (c*16+l15)*64 + kc*32+quad*8), ak[c]);
        av[c] = MFMA16(tf[kc], ld8(ws0+O_WV + (c*16+l15)*64 + kc*32+quad*8), av[c]);
      }
    }
    #pragma unroll
    for (int c=0;c<4;++c){
      #pragma unroll
      for (int r=0;r<4;++r){
        int row = quad*4+r, col = c*16+l15;
        Q [row*72+col] = f2bf(aq[c][r]);
        Kr[row*72+col] = f2bf(ak[c][r]);
      }
      *(ushort4*)(VT + (c*16+l15)*16 + quad*4) = pack4(av[c]);   // V^T[dim][node]
    }
  }
  FENCE();

  // ---- S = (Q K^T)/4 per head (MFMA, K=16 zero-padded); softmax over keys ----
  unsigned short* Pb = AR + A_PB;
  {
    f32x4 accS[4];
    #pragma unroll
    for (int h=0;h<4;++h){
      bf16x8 aQ = hv ? ld8(Q  + l15*72 + h*16 + quad*8) : Z;
      bf16x8 bK = hv ? ld8(Kr + l15*72 + h*16 + quad*8) : Z;
      accS[h] = MFMA16(aQ, bK, z);
    }
    #pragma unroll
    for (int h=0;h<4;++h){
      #pragma unroll
      for (int r=0;r<4;++r){
        float s = accS[h][r]*0.25f;
        float m = s;
        m = fmaxf(m, __shfl_xor(m,1,64));
        m = fmaxf(m, __shfl_xor(m,2,64));
        m = fmaxf(m, __shfl_xor(m,4,64));
        m = fmaxf(m, __shfl_xor(m,8,64));
        float p = __expf(s-m);
        float su = p;
        su += __shfl_xor(su,1,64);
        su += __shfl_xor(su,2,64);
        su += __shfl_xor(su,4,64);
        su += __shfl_xor(su,8,64);
        Pb[(h*16 + quad*4 + r)*16 + l15] = f2bf(p/su);
      }
    }
  }
  FENCE();

  // ---- O = P@V per head -> Ost[16][72] ----
  unsigned short* Ost = AR + A_OST;
  {
    #pragma unroll
    for (int h=0;h<4;++h){
      bf16x8 aP = hv ? ld8(Pb + (h*16+l15)*16 + quad*8) : Z;
      bf16x8 bV = hv ? ld8(VT + (h*16+l15)*16 + quad*8) : Z;
      f32x4 o = MFMA16(aP, bV, z);
      #pragma unroll
      for (int r=0;r<4;++r)
        Ost[(quad*4+r)*72 + h*16+l15] = f2bf(o[r]);
    }
  }
  FENCE();

  // ---- o @ wo, mean over nodes, @ wproj + bproj -> feat ----
  {
    f32x4 ao[4] = {z,z,z,z};
    #pragma unroll
    for (int kc=0;kc<2;++kc){
      bf16x8 a = ld8(Ost + l15*72 + kc*32+quad*8);
      #pragma unroll
      for (int c=0;c<4;++c)
        ao[c] = MFMA16(a, ld8(ws0+O_WO + (c*16+l15)*64 + kc*32+quad*8), ao[c]);
    }
    float* part = (float*)(AR + A_PART);   // [4][64]
    float* fpre = part + 256;              // [64]
    #pragma unroll
    for (int c=0;c<4;++c)
      part[quad*64 + c*16+l15] = ao[c][0]+ao[c][1]+ao[c][2]+ao[c][3];
    FENCE();
    float sm = part[lane] + part[64+lane] + part[128+lane] + part[192+lane];
    fpre[lane] = sm * (1.f/16.f);
    FENCE();
    float a0 = bproj[lane], a1 = bproj[lane+64];
    #pragma unroll 8
    for (int c2=0;c2<64;++c2){
      float f = fpre[c2];
      a0 += f * wproj[c2*128 + lane];
      a1 += f * wproj[c2*128 + lane + 64];
    }
    feat[(size_t)gb*128 + lane]      = f2bf(a0);
    feat[(size_t)gb*128 + lane + 64] = f2bf(a1);
  }
}

// ---------------------------------------------------------------------------
// per-variable fc heads: wg = (kh, 256-row chunk), weights staged to LDS once
// ---------------------------------------------------------------------------
__global__ __launch_bounds__(256,4) void k_heads(
  const unsigned short* __restrict__ ws0,
  const float* __restrict__ fc1b, const float* __restrict__ fc2b,
  float* __restrict__ pred)
{
  __shared__ alignas(16) unsigned short W1s[64*136];   // stride 136
  __shared__ alignas(16) unsigned short W2s[32*72];    // stride 72
  __shared__ alignas(16) unsigned short hh[4*16*72];
  const int tid=threadIdx.x, w=tid>>6, lane=tid&63, quad=lane>>4, l15=lane&15;
  const int kh = blockIdx.x >> 6, chunk = blockIdx.x & 63;
  const unsigned short* featg = ws0 + O_FEAT;
  const unsigned short* W1g = ws0 + O_FC1 + kh*8192;   // [64][128]
  const unsigned short* W2g = ws0 + O_FC2 + kh*2048;   // [32][64]
  // cooperative staging
  #pragma unroll
  for (int it=0; it<4; ++it){
    int i = it*256 + tid;            // 1024 uint4 for W1
    int row = i>>4, seg = i&15;
    *(uint4*)(W1s + row*136 + seg*8) = *(const uint4*)(W1g + row*128 + seg*8);
  }
  {
    int i = tid;                     // 256 uint4 for W2
    int row = i>>3, seg = i&7;
    *(uint4*)(W2s + row*72 + seg*8) = *(const uint4*)(W2g + row*64 + seg*8);
  }
  float bb1[4], bb2[2];
  #pragma unroll
  for (int c=0;c<4;++c) bb1[c] = fc1b[kh*64 + c*16+l15];
  #pragma unroll
  for (int c=0;c<2;++c) bb2[c] = (c*16+l15 < 24) ? fc2b[kh*24 + c*16+l15] : 0.f;
  __syncthreads();

  unsigned short* hw = hh + w*1152;
  const f32x4 z = {0.f,0.f,0.f,0.f};
  #pragma unroll 1
  for (int t=0;t<4;++t){
    const int rb = chunk*256 + (w*4+t)*16;
    f32x4 acc[4] = {z,z,z,z};
    #pragma unroll
    for (int kc=0;kc<4;++kc){
      bf16x8 a = ld8(featg + (size_t)(rb+l15)*128 + kc*32+quad*8);
      #pragma unroll
      for (int c=0;c<4;++c)
        acc[c] = MFMA16(a, ld8(W1s + (c*16+l15)*136 + kc*32+quad*8), acc[c]);
    }
    #pragma unroll
    for (int c=0;c<4;++c){
      #pragma unroll
      for (int r=0;r<4;++r)
        hw[(quad*4+r)*72 + c*16+l15] = f2bf(fmaxf(acc[c][r]+bb1[c], 0.f));
    }
    FENCE();
    f32x4 acc2[2] = {z,z};
    #pragma unroll
    for (int kc=0;kc<2;++kc){
      bf16x8 a = ld8(hw + l15*72 + kc*32+quad*8);
      #pragma unroll
      for (int c=0;c<2;++c)
        acc2[c] = MFMA16(a, ld8(W2s + (c*16+l15)*72 + kc*32+quad*8), acc2[c]);
    }
    #pragma unroll
    for (int c=0;c<2;++c){
      int col = c*16+l15;
      if (col < 24){
        #pragma unroll
        for (int r=0;r<4;++r)
          pred[(size_t)kh*393216 + (size_t)(rb+quad*4+r)*24 + col] = acc2[c][r] + bb2[c];
      }
    }
    FENCE();
  }
}

// yb output = y.reshape -> exact copy
__global__ __launch_bounds__(256) void k_copy(const float4* __restrict__ y,
                                              float4* __restrict__ o)
{
  int i = blockIdx.x*256 + threadIdx.x;   // exactly 1572864 float4s
  o[i] = y[i];
}

// ---------------------------------------------------------------------------
extern "C" void kernel_launch(void* const* d_in, const int* in_sizes, int n_in,
                              void* d_out, int out_size, void* d_ws, size_t ws_size,
                              hipStream_t stream) {
  const float* x    = (const float*)d_in[0];
  const float* y    = (const float*)d_in[1];
  const int*   ei   = (const int*)d_in[2];
  const float* w1l  = (const float*)d_in[4];
  const float* w1r  = (const float*)d_in[5];
  const float* b1   = (const float*)d_in[6];
  const float* w2l  = (const float*)d_in[7];
  const float* w2r  = (const float*)d_in[8];
  const float* b2   = (const float*)d_in[9];
  const float* w3l  = (const float*)d_in[10];
  const float* w3r  = (const float*)d_in[11];
  const float* b3   = (const float*)d_in[12];
  const float* tcnw = (const float*)d_in[13];
  const float* tcnb = (const float*)d_in[14];
  const float* wq   = (const float*)d_in[15];
  const float* wk   = (const float*)d_in[16];
  const float* wv   = (const float*)d_in[17];
  const float* wo   = (const float*)d_in[18];
  const float* wpr  = (const float*)d_in[19];
  const float* bpr  = (const float*)d_in[20];
  const float* fc1w = (const float*)d_in[21];
  const float* fc1b = (const float*)d_in[22];
  const float* fc2w = (const float*)d_in[23];
  const float* fc2b = (const float*)d_in[24];

  unsigned short* W = (unsigned short*)d_ws;
  float* out = (float*)d_out;

  k_prep<<<1120, 256, 0, stream>>>(w1l,w1r,w2l,w2r,w3l,w3r,tcnw,wq,wk,wv,wo,fc1w,fc2w,W);
  k_fused<<<NGR/4, 256, 0, stream>>>(x, ei + EDGES, b1,b2,b3,tcnb,wpr,bpr, W, W + O_FEAT);
  k_heads<<<1024, 256, 0, stream>>>(W, fc1b, fc2b, out);
  k_copy<<<6144, 256, 0, stream>>>((const float4*)y, (float4*)(out + PRED_ELEMS));
}